// Round 6
// baseline (256.900 us; speedup 1.0000x reference)
//
#include <hip/hip_runtime.h>

// Problem constants (from reference setup_inputs)
#define B    128
#define H    14
#define W    14
#define C    512
#define NCLS 200
#define HW   (H * W)          // 196
#define TP_DIM 15             // t_p is [15,15,14,14]
#define SENT_OFF ((14 * TP_DIM + 14) * HW)  // sentinel template row offset

typedef float  v4f __attribute__((ext_vector_type(4)));
typedef int    v4i __attribute__((ext_vector_type(4)));

// ---------------------------------------------------------------------------
// Fused kernel v5 (resubmit — round-5 failure was container infra, not the
// kernel): everything-in-registers, single streaming burst.
//
// Ownership: block (b, quarter) = batch b, channels [q*128,+128).
//   Thread (sl = tid>>5, cg = tid&31): spatial slice [12*sl, 12*sl+12)
//   (sl==15 additionally owns [192,196)) x channels c0..c0+3.
//
//   Phase 1: load the thread's x slice into REGISTERS (12-16 v4f, contiguous
//     512 B per half-wave), in-thread argmax (ascending s, strict '>').
//     LDS fold over sl ascending: per-sl s-ranges are contiguous and ordered
//     by sl, so strict '>' preserves jnp.argmax first-occurrence globally.
//     gt-argmax runs concurrently on wave 1 during the combine.
//
//   Phase 2: per-thread t_p row segments gathered into REGISTERS (4 rows x
//     12-16 contiguous floats, 16-B aligned: 12*sl % 4 == 0; t_p is 176 KB
//     L2-resident). Only ONE load stream left (ctpl) + 3 nontemporal store
//     streams; x and t come from registers. out_x needs no load at all.
//     All gathers + ctpl loads issue behind a single barrier -> max MLP.
//
//   Barriers: 2 (was 4). LDS: 16.5 KB (was 52 KB). x read exactly once.
//   XCD swizzle kept: quarter-blocks of batch b are blockIdx ≡ b (mod 8).
// ---------------------------------------------------------------------------
__global__ __launch_bounds__(512) void fused_kernel(
        const float* __restrict__ x,
        const float* __restrict__ gt,
        const float* __restrict__ t_p,
        const float* __restrict__ ctpl,
        float*       __restrict__ out) {
    __shared__ v4f s_best[16][32];
    __shared__ v4i s_idx[16][32];
    __shared__ int s_off[128];
    __shared__ int s_cls;

    const int tid     = threadIdx.x;
    const int b       = blockIdx.x & 127;   // XCD swizzle (see header)
    const int quarter = blockIdx.x >> 7;
    const int cg      = tid & 31;           // channel group (4 ch) 0..31
    const int sl      = tid >> 5;           // spatial-slice id 0..15
    const int c0      = quarter * 128 + cg * 4;
    const int cl      = cg * 4;             // local channel base
    const bool extra  = (sl == 15);         // owns the 4-position tail too
    const int  sbeg   = 12 * sl;

    const float* __restrict__ xp = x + (size_t)b * HW * C + c0;

    // ---------------- Phase 1: x slice -> registers, in-thread argmax ------
    v4f xr[16];
#pragma unroll
    for (int k = 0; k < 12; ++k)
        xr[k] = *(const v4f*)(xp + (size_t)(sbeg + k) * C);
    if (extra) {
#pragma unroll
        for (int k = 12; k < 16; ++k)      // s = 192..195
            xr[k] = *(const v4f*)(xp + (size_t)(sbeg + k) * C);
    }

    v4f best = xr[0];
    v4i bidx = (v4i){sbeg, sbeg, sbeg, sbeg};
#pragma unroll
    for (int k = 1; k < 12; ++k) {
        const int s = sbeg + k;
        v4f v = xr[k];
        if (v.x > best.x) { best.x = v.x; bidx.x = s; }  // strict > = first occ.
        if (v.y > best.y) { best.y = v.y; bidx.y = s; }
        if (v.z > best.z) { best.z = v.z; bidx.z = s; }
        if (v.w > best.w) { best.w = v.w; bidx.w = s; }
    }
    if (extra) {
#pragma unroll
        for (int k = 12; k < 16; ++k) {
            const int s = sbeg + k;
            v4f v = xr[k];
            if (v.x > best.x) { best.x = v.x; bidx.x = s; }
            if (v.y > best.y) { best.y = v.y; bidx.y = s; }
            if (v.z > best.z) { best.z = v.z; bidx.z = s; }
            if (v.w > best.w) { best.w = v.w; bidx.w = s; }
        }
    }
    s_best[sl][cg] = best;
    s_idx[sl][cg]  = bidx;
    __syncthreads();

    // ---------------- Combine (tid<32) + gt-argmax (wave 1) ----------------
    if (tid < 32) {
        v4f cb = s_best[0][tid];
        v4i ci = s_idx[0][tid];
#pragma unroll
        for (int k = 1; k < 16; ++k) {      // ascending s-ranges: '>' = first
            v4f p = s_best[k][tid];
            v4i q = s_idx[k][tid];
            if (p.x > cb.x) { cb.x = p.x; ci.x = q.x; }
            if (p.y > cb.y) { cb.y = p.y; ci.y = q.y; }
            if (p.z > cb.z) { cb.z = p.z; ci.z = q.z; }
            if (p.w > cb.w) { cb.w = p.w; ci.w = q.w; }
        }
        v4i o;
        o.x = (cb.x == 0.0f) ? SENT_OFF : ((ci.x / W) * TP_DIM + (ci.x % W)) * HW;
        o.y = (cb.y == 0.0f) ? SENT_OFF : ((ci.y / W) * TP_DIM + (ci.y % W)) * HW;
        o.z = (cb.z == 0.0f) ? SENT_OFF : ((ci.z / W) * TP_DIM + (ci.z % W)) * HW;
        o.w = (cb.w == 0.0f) ? SENT_OFF : ((ci.w / W) * TP_DIM + (ci.w % W)) * HW;
        *(v4i*)&s_off[tid * 4] = o;
    } else if (tid >= 64 && tid < 128) {
        // wave 1: class argmax over gt[b], index-min tie-break
        const int lane = tid - 64;
        const float* __restrict__ g = gt + (size_t)b * NCLS;
        float gb = -__builtin_inff();
        int   gi = NCLS;
        for (int i = lane; i < NCLS; i += 64) {   // ascending per lane
            float v = g[i];
            if (v > gb) { gb = v; gi = i; }       // keeps smallest index
        }
#pragma unroll
        for (int d = 1; d < 64; d <<= 1) {
            float ov = __shfl_xor(gb, d);
            int   oi = __shfl_xor(gi, d);
            if (ov > gb || (ov == gb && oi < gi)) { gb = ov; gi = oi; }
        }
        if (lane == 0) s_cls = gi;
    }
    __syncthreads();

    // ---------------- Phase 2: template gather -> regs, stream out ---------
    const int klass = s_cls;
    const v4i off = *(const v4i*)&s_off[cl];   // t_p rows for c0..c0+3

    // tr[j][m]: channel j, spatial s = sbeg+4m .. +3 (16-B aligned)
    v4f tr[4][4];
#pragma unroll
    for (int m = 0; m < 3; ++m) {
        tr[0][m] = *(const v4f*)(t_p + off.x + sbeg + 4 * m);
        tr[1][m] = *(const v4f*)(t_p + off.y + sbeg + 4 * m);
        tr[2][m] = *(const v4f*)(t_p + off.z + sbeg + 4 * m);
        tr[3][m] = *(const v4f*)(t_p + off.w + sbeg + 4 * m);
    }
    if (extra) {
        tr[0][3] = *(const v4f*)(t_p + off.x + sbeg + 12);
        tr[1][3] = *(const v4f*)(t_p + off.y + sbeg + 12);
        tr[2][3] = *(const v4f*)(t_p + off.z + sbeg + 12);
        tr[3][3] = *(const v4f*)(t_p + off.w + sbeg + 12);
    }

    const size_t plane = (size_t)B * HW * C;
    const float* __restrict__ ctp = ctpl + (size_t)klass * HW * C;

#pragma unroll
    for (int m = 0; m < 4; ++m) {           // quad m: s0 = sbeg + 4m
        if (m == 3 && !extra) break;
        const int s0 = sbeg + 4 * m;
        const size_t base = ((size_t)b * HW + s0) * C + c0;
        const float* __restrict__ cp = ctp + (size_t)s0 * C + c0;
        float* __restrict__ out_m = out + base;
        float* __restrict__ out_x = out + plane + base;
        float* __restrict__ out_t = out + 2 * plane + base;

#pragma unroll
        for (int i = 0; i < 4; ++i) {
            v4f xv = xr[4 * m + i];          // registers — no load
            v4f ct = *(const v4f*)(cp + (size_t)i * C);
            v4f tt;                          // transpose from per-channel regs
            tt.x = tr[0][m][i];
            tt.y = tr[1][m][i];
            tt.z = tr[2][m][i];
            tt.w = tr[3][m][i];
            v4f mm;
            mm.x = fmaxf(xv.x * tt.x, 0.0f) * ct.x;
            mm.y = fmaxf(xv.y * tt.y, 0.0f) * ct.y;
            mm.z = fmaxf(xv.z * tt.z, 0.0f) * ct.z;
            mm.w = fmaxf(xv.w * tt.w, 0.0f) * ct.w;
            __builtin_nontemporal_store(mm, (v4f*)(out_m + (size_t)i * C));
            __builtin_nontemporal_store(xv, (v4f*)(out_x + (size_t)i * C));
            __builtin_nontemporal_store(tt, (v4f*)(out_t + (size_t)i * C));
        }
    }
}

// ---------------------------------------------------------------------------
extern "C" void kernel_launch(void* const* d_in, const int* in_sizes, int n_in,
                              void* d_out, int out_size, void* d_ws, size_t ws_size,
                              hipStream_t stream) {
    const float* x    = (const float*)d_in[0];  // [B,H,W,C]
    const float* gt   = (const float*)d_in[1];  // [B,NCLS]
    const float* t_p  = (const float*)d_in[2];  // [15,15,H,W]
    const float* ctpl = (const float*)d_in[3];  // [NCLS,H,W,C]
    float* out = (float*)d_out;                 // [3, B,H,W,C] flat

    hipLaunchKernelGGL(fused_kernel,
                       dim3(4 * B), dim3(512), 0, stream,
                       x, gt, t_p, ctpl, out);
}